// Round 4
// baseline (188.728 us; speedup 1.0000x reference)
//
#include <hip/hip_runtime.h>
#include <hip/hip_bf16.h>

typedef __attribute__((ext_vector_type(8))) short short8;
typedef __attribute__((ext_vector_type(4))) float floatx4;

#define GLOAD_LDS16(src, dst) \
  __builtin_amdgcn_global_load_lds((const __attribute__((address_space(1))) unsigned int*)(src), \
      (__attribute__((address_space(3))) unsigned int*)(dst), 16, 0, 0)

__device__ __forceinline__ short f2bf(float f) {
    __hip_bfloat16 h = __float2bfloat16(f);
    return *reinterpret_cast<short*>(&h);
}

__device__ __forceinline__ floatx4 mfma16(short8 a, short8 b, floatx4 c) {
    return __builtin_amdgcn_mfma_f32_16x16x32_bf16(a, b, c, 0, 0, 0);
}

// ---------------- Kernel 1: W -> WT (bf16, transposed, concat q|k|v) ----------------
__global__ __launch_bounds__(256) void wconv_kernel(const float* __restrict__ Wq,
                                                    const float* __restrict__ Wk,
                                                    const float* __restrict__ Wv,
                                                    __hip_bfloat16* __restrict__ WT) {
    int n = blockIdx.x;                       // 0..767
    const float* W = (n < 256) ? Wq : (n < 512 ? Wk : Wv);
    int nl = n & 255;
    __hip_bfloat16* dst = WT + (size_t)n * 1024;
    for (int kk = threadIdx.x; kk < 1024; kk += 256)
        dst[kk] = __float2bfloat16(W[(size_t)kk * 256 + nl]);
}

// ---------------- Kernel 2: projections  q,k,v = x @ W + b ----------------
// 128x128 tile, BK=64. 4 waves stacked in m (each wave: 32 m-rows x 128 n-cols).
// A: fp32 x -> regs -> cvt -> MFMA directly (lane-local rows, no LDS, 1-deep prefetch).
// B: WT bf16 via global_load_lds, DOUBLE-buffered, one barrier per K-step (T3 2-phase).
__global__ __launch_bounds__(256) void proj_kernel(const float* __restrict__ x,
                                                   const __hip_bfloat16* __restrict__ WT,
                                                   const float* __restrict__ bq,
                                                   const float* __restrict__ bk,
                                                   const float* __restrict__ bv,
                                                   __hip_bfloat16* __restrict__ qo,
                                                   __hip_bfloat16* __restrict__ ko,
                                                   __hip_bfloat16* __restrict__ vo) {
    __shared__ __align__(16) __hip_bfloat16 Bs[2][128 * 64];   // 2 x 16 KB
    char* BsB = (char*)Bs;

    const int tid = threadIdx.x;
    // XCD-chunk bijective swizzle: nwg=1536, 8 XCDs, 192 per XCD; 6 n-tiles of an
    // m-panel are consecutive -> same XCD L2 serves the shared x panel.
    const int bid = blockIdx.x;
    const int wgid = (bid & 7) * 192 + (bid >> 3);
    const int ntile = wgid % 6;             // 0..5 over concat-768 n
    const int m0 = (wgid / 6) * 128;
    const int n0 = ntile * 128;
    const int wid = tid >> 6, lane = tid & 63;
    const int l15 = lane & 15, lg = lane >> 4;

    floatx4 acc[2][8];
#pragma unroll
    for (int mt = 0; mt < 2; ++mt)
#pragma unroll
        for (int nt = 0; nt < 8; ++nt) acc[mt][nt] = (floatx4){0.f, 0.f, 0.f, 0.f};

    // lane-local A base: row m0 + wid*32 + l15 (+ mt*16), col lg*8 (+ kt*64 + ks*32)
    const float* xlane = x + (size_t)(m0 + wid * 32 + l15) * 1024 + lg * 8;

    floatx4 ap[2][2][2];    // [mt][ks][half] prefetched fp32 A for next K-step

    // ---- prologue: A(0) loads + stage B(0) -> Bs[0]
#pragma unroll
    for (int mt = 0; mt < 2; ++mt)
#pragma unroll
        for (int ks = 0; ks < 2; ++ks) {
            const float* s = xlane + mt * 16 * 1024 + ks * 32;
            ap[mt][ks][0] = *(const floatx4*)s;
            ap[mt][ks][1] = *(const floatx4*)(s + 4);
        }
#pragma unroll
    for (int s = 0; s < 4; ++s) {
        int o = s * 4096 + tid * 16;
        int row = o >> 7;                         // 128 B per row
        int so = o ^ ((row & 7) << 4);
        const __hip_bfloat16* src = WT + (size_t)(n0 + row) * 1024 + ((so & 127) >> 1);
        GLOAD_LDS16(src, BsB + o);
    }
    __syncthreads();

    for (int kt = 0; kt < 16; ++kt) {
        const int buf = kt & 1;
        // ---- convert prefetched A (loads completed by the preceding barrier drain)
        short8 afr[2][2];
#pragma unroll
        for (int mt = 0; mt < 2; ++mt)
#pragma unroll
            for (int ks = 0; ks < 2; ++ks) {
                short8 h;
                h[0] = f2bf(ap[mt][ks][0][0]); h[1] = f2bf(ap[mt][ks][0][1]);
                h[2] = f2bf(ap[mt][ks][0][2]); h[3] = f2bf(ap[mt][ks][0][3]);
                h[4] = f2bf(ap[mt][ks][1][0]); h[5] = f2bf(ap[mt][ks][1][1]);
                h[6] = f2bf(ap[mt][ks][1][2]); h[7] = f2bf(ap[mt][ks][1][3]);
                afr[mt][ks] = h;
            }
        // ---- issue next K-step's A loads + B stage (fly during compute below)
        if (kt < 15) {
#pragma unroll
            for (int mt = 0; mt < 2; ++mt)
#pragma unroll
                for (int ks = 0; ks < 2; ++ks) {
                    const float* s = xlane + mt * 16 * 1024 + (kt + 1) * 64 + ks * 32;
                    ap[mt][ks][0] = *(const floatx4*)s;
                    ap[mt][ks][1] = *(const floatx4*)(s + 4);
                }
            char* nxt = BsB + (buf ^ 1) * 16384;
#pragma unroll
            for (int s = 0; s < 4; ++s) {
                int o = s * 4096 + tid * 16;
                int row = o >> 7;
                int so = o ^ ((row & 7) << 4);
                const __hip_bfloat16* src = WT + (size_t)(n0 + row) * 1024 + (kt + 1) * 64 + ((so & 127) >> 1);
                GLOAD_LDS16(src, nxt + o);
            }
        }
        // ---- compute on Bs[buf]
        char* cur = BsB + buf * 16384;
#pragma unroll
        for (int ks = 0; ks < 2; ++ks)
#pragma unroll
            for (int nt = 0; nt < 8; ++nt) {
                int row = nt * 16 + l15;
                int rb = row * 128, msk = (row & 7) << 4;
                short8 b8 = *(const short8*)(cur + rb + ((ks * 64 + lg * 16) ^ msk));
                acc[0][nt] = mfma16(afr[0][ks], b8, acc[0][nt]);
                acc[1][nt] = mfma16(afr[1][ks], b8, acc[1][nt]);
            }
        __syncthreads();
    }

    // ---- epilogue: bias (+ log2e/16 scale for q), bf16 store
#pragma unroll
    for (int nt = 0; nt < 8; ++nt) {
        int g = n0 + nt * 16 + l15;             // 0..767 (wave-uniform mat)
        int mat = g >> 8;                       // 0=q 1=k 2=v
        const float* bias = (mat == 0) ? bq : (mat == 1 ? bk : bv);
        __hip_bfloat16* ob = (mat == 0) ? qo : (mat == 1 ? ko : vo);
        float scale = (mat == 0) ? 0.09016844005556021f : 1.0f;  // log2(e)/16
        int c = g & 255;
        float bval = bias[c];
#pragma unroll
        for (int mt = 0; mt < 2; ++mt) {
            int row = m0 + wid * 32 + mt * 16 + lg * 4;
#pragma unroll
            for (int r = 0; r < 4; ++r)
                ob[(size_t)(row + r) * 256 + c] = __float2bfloat16((acc[mt][nt][r] + bval) * scale);
        }
    }
}

// ---------------- Kernel 3: causal flash attention ----------------
__global__ __launch_bounds__(256) void attn_kernel(const __hip_bfloat16* __restrict__ q,
                                                   const __hip_bfloat16* __restrict__ k,
                                                   const __hip_bfloat16* __restrict__ v,
                                                   float* __restrict__ out) {
    __shared__ __align__(16) __hip_bfloat16 Ks[64 * 256];    // 32 KB, swizzled rows of 512B
    __shared__ __align__(16) __hip_bfloat16 VTs[256 * 64];   // 32 KB, V^T, swizzled rows of 128B
    __shared__ __align__(16) __hip_bfloat16 Ps[4][16 * 64];  // 8 KB, per-wave P
    char* KsB = (char*)Ks;
    char* VTB = (char*)VTs;

    const int tid = threadIdx.x;
    // XCD-chunk bijective swizzle: nwg=512, 8 XCDs, 64 per XCD.
    const int bid = blockIdx.x;
    const int wgid = (bid & 7) * 64 + (bid >> 3);
    const int qb = wgid & 7, b = wgid >> 3;
    const int wid = tid >> 6, lane = tid & 63;
    const int l15 = lane & 15, lg = lane >> 4;
    char* PsB = (char*)(&Ps[wid][0]);

    short8 qf[8];
    const __hip_bfloat16* qrow = q + ((size_t)(b * 512 + qb * 64 + wid * 16 + l15)) * 256;
#pragma unroll
    for (int ks = 0; ks < 8; ++ks) qf[ks] = *(const short8*)(qrow + ks * 32 + lg * 8);

    float m_[4], lsum[4];
    floatx4 o[16];
#pragma unroll
    for (int r = 0; r < 4; ++r) { m_[r] = -1e30f; lsum[r] = 0.f; }
#pragma unroll
    for (int dt = 0; dt < 16; ++dt) o[dt] = (floatx4){0.f, 0.f, 0.f, 0.f};

    const int vkv = lane;
    const int vd0 = wid * 8;

    for (int c = 0; c <= qb; ++c) {
        const size_t kvbase = (size_t)(b * 512 + c * 64) * 256;
#pragma unroll
        for (int s = 0; s < 8; ++s) {
            int o_ = s * 4096 + tid * 16;
            int row = o_ >> 9;
            int so = o_ ^ ((row & 7) << 4);
            const __hip_bfloat16* src = k + kvbase + (size_t)row * 256 + ((so & 511) >> 1);
            GLOAD_LDS16(src, KsB + o_);
        }
#pragma unroll
        for (int it = 0; it < 8; ++it) {
            int dbase = vd0 + it * 32;
            short8 vv = *(const short8*)(v + kvbase + (size_t)vkv * 256 + dbase);
#pragma unroll
            for (int j = 0; j < 8; ++j) {
                int d = dbase + j;
                int addr = (d * 128 + vkv * 2) ^ ((d & 7) << 4);
                *(short*)(VTB + addr) = vv[j];
            }
        }
        __syncthreads();

        floatx4 s4[4];
#pragma unroll
        for (int t = 0; t < 4; ++t) s4[t] = (floatx4){0.f, 0.f, 0.f, 0.f};
#pragma unroll
        for (int ks = 0; ks < 8; ++ks) {
#pragma unroll
            for (int t = 0; t < 4; ++t) {
                int kv = t * 16 + l15;
                short8 kf = *(const short8*)(KsB + kv * 512 + ((ks * 64 + lg * 16) ^ ((kv & 7) << 4)));
                s4[t] = mfma16(qf[ks], kf, s4[t]);
            }
        }
        if (c == qb) {
#pragma unroll
            for (int t = 0; t < 4; ++t) {
                int kvl = t * 16 + l15;
#pragma unroll
                for (int r = 0; r < 4; ++r)
                    if (kvl > wid * 16 + lg * 4 + r) s4[t][r] = -1e30f;
            }
        }
        float pm[4], alpha[4], rs[4];
#pragma unroll
        for (int r = 0; r < 4; ++r)
            pm[r] = fmaxf(fmaxf(s4[0][r], s4[1][r]), fmaxf(s4[2][r], s4[3][r]));
#pragma unroll
        for (int off = 1; off <= 8; off <<= 1)
#pragma unroll
            for (int r = 0; r < 4; ++r) pm[r] = fmaxf(pm[r], __shfl_xor(pm[r], off));
#pragma unroll
        for (int r = 0; r < 4; ++r) {
            float mn = fmaxf(m_[r], pm[r]);
            alpha[r] = exp2f(m_[r] - mn);
            m_[r] = mn;
        }
#pragma unroll
        for (int t = 0; t < 4; ++t)
#pragma unroll
            for (int r = 0; r < 4; ++r) s4[t][r] = exp2f(s4[t][r] - m_[r]);
#pragma unroll
        for (int r = 0; r < 4; ++r) rs[r] = s4[0][r] + s4[1][r] + s4[2][r] + s4[3][r];
#pragma unroll
        for (int off = 1; off <= 8; off <<= 1)
#pragma unroll
            for (int r = 0; r < 4; ++r) rs[r] += __shfl_xor(rs[r], off);
#pragma unroll
        for (int r = 0; r < 4; ++r) lsum[r] = lsum[r] * alpha[r] + rs[r];
#pragma unroll
        for (int dt = 0; dt < 16; ++dt) {
            o[dt][0] *= alpha[0]; o[dt][1] *= alpha[1];
            o[dt][2] *= alpha[2]; o[dt][3] *= alpha[3];
        }
#pragma unroll
        for (int t = 0; t < 4; ++t)
#pragma unroll
            for (int r = 0; r < 4; ++r) {
                int qq = lg * 4 + r;
                int addr = (qq * 128 + (t * 16 + l15) * 2) ^ ((qq & 7) << 4);
                *(short*)(PsB + addr) = f2bf(s4[t][r]);
            }
#pragma unroll
        for (int h = 0; h < 2; ++h) {
            short8 pa = *(const short8*)(PsB + l15 * 128 + ((h * 64 + lg * 16) ^ ((l15 & 7) << 4)));
#pragma unroll
            for (int dt = 0; dt < 16; ++dt) {
                int d = dt * 16 + l15;
                short8 vb = *(const short8*)(VTB + d * 128 + ((h * 64 + lg * 16) ^ ((d & 7) << 4)));
                o[dt] = mfma16(pa, vb, o[dt]);
            }
        }
        __syncthreads();
    }

    float inv[4];
#pragma unroll
    for (int r = 0; r < 4; ++r) inv[r] = 1.0f / lsum[r];
    size_t obase = ((size_t)(b * 512 + qb * 64 + wid * 16 + lg * 4)) * 256 + l15;
#pragma unroll
    for (int dt = 0; dt < 16; ++dt)
#pragma unroll
        for (int r = 0; r < 4; ++r)
            out[obase + (size_t)r * 256 + dt * 16] = o[dt][r] * inv[r];
}

// ---------------- host launch ----------------
extern "C" void kernel_launch(void* const* d_in, const int* in_sizes, int n_in,
                              void* d_out, int out_size, void* d_ws, size_t ws_size,
                              hipStream_t stream) {
    const float* x  = (const float*)d_in[0];
    const float* Wq = (const float*)d_in[1];
    const float* bq = (const float*)d_in[2];
    const float* Wk = (const float*)d_in[3];
    const float* bk = (const float*)d_in[4];
    const float* Wv = (const float*)d_in[5];
    const float* bv = (const float*)d_in[6];
    float* out = (float*)d_out;

    char* ws = (char*)d_ws;
    __hip_bfloat16* WT = (__hip_bfloat16*)ws;                       // 1.5 MiB @ 0
    __hip_bfloat16* qo = (__hip_bfloat16*)(ws + (2u << 20));        // 16 MiB each
    __hip_bfloat16* ko = qo + (size_t)32768 * 256;
    __hip_bfloat16* vo = ko + (size_t)32768 * 256;

    wconv_kernel<<<dim3(768), dim3(256), 0, stream>>>(Wq, Wk, Wv, WT);
    proj_kernel<<<dim3(1536), dim3(256), 0, stream>>>(x, WT, bq, bk, bv, qo, ko, vo);
    attn_kernel<<<dim3(512), dim3(256), 0, stream>>>(qo, ko, vo, out);
}

// Round 5
// 167.257 us; speedup vs baseline: 1.1284x; 1.1284x over previous
//
#include <hip/hip_runtime.h>
#include <hip/hip_bf16.h>

typedef __attribute__((ext_vector_type(8))) short short8;
typedef __attribute__((ext_vector_type(4))) short short4v;
typedef __attribute__((ext_vector_type(4))) float floatx4;

#define GLOAD_LDS16(src, dst) \
  __builtin_amdgcn_global_load_lds((const __attribute__((address_space(1))) unsigned int*)(src), \
      (__attribute__((address_space(3))) unsigned int*)(dst), 16, 0, 0)

__device__ __forceinline__ short f2bf(float f) {
    __hip_bfloat16 h = __float2bfloat16(f);
    return *reinterpret_cast<short*>(&h);
}

__device__ __forceinline__ floatx4 mfma16(short8 a, short8 b, floatx4 c) {
    return __builtin_amdgcn_mfma_f32_16x16x32_bf16(a, b, c, 0, 0, 0);
}

// ---------------- Kernel 1: W -> WT (bf16, transposed, concat q|k|v) ----------------
__global__ __launch_bounds__(256) void wconv_kernel(const float* __restrict__ Wq,
                                                    const float* __restrict__ Wk,
                                                    const float* __restrict__ Wv,
                                                    __hip_bfloat16* __restrict__ WT) {
    int n = blockIdx.x;                       // 0..767
    const float* W = (n < 256) ? Wq : (n < 512 ? Wk : Wv);
    int nl = n & 255;
    __hip_bfloat16* dst = WT + (size_t)n * 1024;
    for (int kk = threadIdx.x; kk < 1024; kk += 256)
        dst[kk] = __float2bfloat16(W[(size_t)kk * 256 + nl]);
}

// ---------------- Kernel 2: projections  q,k,v = x @ W + b ----------------
// 256x128 tile, BK=64, 8 waves (4m x 2n of 64x64). Counted-vmcnt pipeline (T3+T4):
//   B (WT bf16): global_load_lds, staged 2 K-tiles ahead, double-buffered.
//   A (x fp32):  reg-loaded 2 K-tiles ahead, cvt+ds_write 1 tile ahead (T14 split).
//   Raw s_barrier + asm s_waitcnt vmcnt(10) -- never drains to 0 in the loop.
__global__ __launch_bounds__(512) void proj_kernel(const float* __restrict__ x,
                                                   const __hip_bfloat16* __restrict__ WT,
                                                   const float* __restrict__ bq,
                                                   const float* __restrict__ bk,
                                                   const float* __restrict__ bv,
                                                   __hip_bfloat16* __restrict__ qo,
                                                   __hip_bfloat16* __restrict__ ko,
                                                   __hip_bfloat16* __restrict__ vo) {
    __shared__ __align__(16) char Ab[2][32768];   // 256x64 bf16, swizzled 128B rows
    __shared__ __align__(16) char Bb[2][16384];   // 128x64 bf16, swizzled 128B rows

    const int tid = threadIdx.x;
    // XCD-chunk bijective swizzle: nwg=768, 8 XCDs, 96 per XCD; 6 n-tiles of an
    // m-panel consecutive -> same XCD L2 serves the shared x panel.
    const int bid = blockIdx.x;
    const int wgid = (bid & 7) * 96 + (bid >> 3);
    const int ntile = wgid % 6;
    const int m0 = (wgid / 6) * 256;
    const int n0 = ntile * 128;
    const int wid = tid >> 6, lane = tid & 63;
    const int wm = wid >> 1, wn = wid & 1;
    const int l15 = lane & 15, lg = lane >> 4;

    // A reg-stage mapping: row = s*32 + (tid>>4), fp32 col = (tid&15)*4
    const int ar_row = tid >> 4;
    const int ar_colf = (tid & 15) * 4;
    const float* xA = x + (size_t)m0 * 1024;

    floatx4 acc[4][4];
#pragma unroll
    for (int i = 0; i < 4; ++i)
#pragma unroll
        for (int j = 0; j < 4; ++j) acc[i][j] = (floatx4){0.f, 0.f, 0.f, 0.f};

    floatx4 ra[8], rb[8];

#define STAGE_B(KT, BUFPTR) do {                                                     \
    _Pragma("unroll")                                                                \
    for (int s = 0; s < 2; ++s) {                                                    \
        int o = s * 8192 + tid * 16;                                                 \
        int row = o >> 7;                                                            \
        int so = o ^ ((row & 7) << 4);                                               \
        const __hip_bfloat16* src = WT + (size_t)(n0 + row) * 1024 + (KT) * 64       \
                                    + ((so & 127) >> 1);                             \
        GLOAD_LDS16(src, (BUFPTR) + o);                                              \
    } } while (0)

#define LOAD_A(KT, R) do {                                                           \
    _Pragma("unroll")                                                                \
    for (int s = 0; s < 8; ++s)                                                      \
        R[s] = *(const floatx4*)(xA + (size_t)(s * 32 + ar_row) * 1024               \
                                 + (KT) * 64 + ar_colf);                             \
    } while (0)

#define CVT_WRITE_A(R, ABUF) do {                                                    \
    _Pragma("unroll")                                                                \
    for (int s = 0; s < 8; ++s) {                                                    \
        int row = s * 32 + ar_row;                                                   \
        int addr = row * 128 + ((ar_colf * 2) ^ ((row & 7) << 4));                   \
        short4v h4;                                                                  \
        h4[0] = f2bf(R[s][0]); h4[1] = f2bf(R[s][1]);                                \
        h4[2] = f2bf(R[s][2]); h4[3] = f2bf(R[s][3]);                                \
        *(short4v*)((ABUF) + addr) = h4;                                             \
    } } while (0)

#define COMPUTE(ABUF, BBUF) do {                                                     \
    _Pragma("unroll")                                                                \
    for (int ks = 0; ks < 2; ++ks) {                                                 \
        short8 af[4], bf8[4];                                                        \
        _Pragma("unroll")                                                            \
        for (int mt = 0; mt < 4; ++mt) {                                             \
            int row = wm * 64 + mt * 16 + l15;                                       \
            af[mt] = *(const short8*)((ABUF) + row * 128                             \
                     + ((ks * 64 + lg * 16) ^ ((row & 7) << 4)));                    \
        }                                                                            \
        _Pragma("unroll")                                                            \
        for (int nt = 0; nt < 4; ++nt) {                                             \
            int row = wn * 64 + nt * 16 + l15;                                       \
            bf8[nt] = *(const short8*)((BBUF) + row * 128                            \
                      + ((ks * 64 + lg * 16) ^ ((row & 7) << 4)));                   \
        }                                                                            \
        __builtin_amdgcn_s_setprio(1);                                               \
        _Pragma("unroll")                                                            \
        for (int mt = 0; mt < 4; ++mt)                                               \
            _Pragma("unroll")                                                        \
            for (int nt = 0; nt < 4; ++nt)                                           \
                acc[mt][nt] = mfma16(af[mt], bf8[nt], acc[mt][nt]);                  \
        __builtin_amdgcn_s_setprio(0);                                               \
    } } while (0)

#define BODY(T, RL, RC) do {                                                         \
    __builtin_amdgcn_sched_barrier(0);                                               \
    asm volatile("s_waitcnt vmcnt(10) lgkmcnt(0)" ::: "memory");                     \
    __builtin_amdgcn_sched_barrier(0);                                               \
    __builtin_amdgcn_s_barrier();                                                    \
    __builtin_amdgcn_sched_barrier(0);                                               \
    { int tp2 = ((T) + 2 > 15) ? 15 : (T) + 2; LOAD_A(tp2, RL); }                    \
    COMPUTE(Ab[(T) & 1], Bb[(T) & 1]);                                               \
    __builtin_amdgcn_sched_barrier(0);                                               \
    __builtin_amdgcn_s_barrier();                                                    \
    __builtin_amdgcn_sched_barrier(0);                                               \
    { int tp2 = ((T) + 2 > 15) ? 15 : (T) + 2; STAGE_B(tp2, Bb[(T) & 1]); }          \
    CVT_WRITE_A(RC, Ab[((T) + 1) & 1]);                                              \
    } while (0)

    // ---- prologue: establish depth-2 pipeline (outstanding: B1(2)+Areg1(8) at loop top)
    STAGE_B(0, Bb[0]);
    LOAD_A(0, ra);
    STAGE_B(1, Bb[1]);
    LOAD_A(1, rb);
    CVT_WRITE_A(ra, Ab[0]);      // compiler inserts vmcnt wait for ra (10 younger fly)

    for (int tt = 0; tt < 8; ++tt) {
        BODY(2 * tt, ra, rb);        // even T: load Areg(T+2)->ra, cvt rb (tile T+1)
        BODY(2 * tt + 1, rb, ra);    // odd  T: load Areg(T+2)->rb, cvt ra
    }

#undef BODY
#undef COMPUTE
#undef CVT_WRITE_A
#undef LOAD_A
#undef STAGE_B

    // ---- epilogue: bias (+ log2e/16 scale for q), bf16 store
#pragma unroll
    for (int nt = 0; nt < 4; ++nt) {
        int g = n0 + wn * 64 + nt * 16 + l15;   // 0..767; mat uniform per (wave,nt)
        int mat = g >> 8;                       // 0=q 1=k 2=v
        const float* bias = (mat == 0) ? bq : (mat == 1 ? bk : bv);
        __hip_bfloat16* ob = (mat == 0) ? qo : (mat == 1 ? ko : vo);
        float scale = (mat == 0) ? 0.09016844005556021f : 1.0f;  // log2(e)/16
        int c = g & 255;
        float bval = bias[c];
#pragma unroll
        for (int mt = 0; mt < 4; ++mt) {
            int row = m0 + wm * 64 + mt * 16 + lg * 4;
#pragma unroll
            for (int r = 0; r < 4; ++r)
                ob[(size_t)(row + r) * 256 + c] = __float2bfloat16((acc[mt][nt][r] + bval) * scale);
        }
    }
}

// ---------------- Kernel 3: causal flash attention ----------------
__global__ __launch_bounds__(256) void attn_kernel(const __hip_bfloat16* __restrict__ q,
                                                   const __hip_bfloat16* __restrict__ k,
                                                   const __hip_bfloat16* __restrict__ v,
                                                   float* __restrict__ out) {
    __shared__ __align__(16) __hip_bfloat16 Ks[64 * 256];    // 32 KB, swizzled rows of 512B
    __shared__ __align__(16) __hip_bfloat16 VTs[256 * 64];   // 32 KB, V^T, swizzled rows of 128B
    __shared__ __align__(16) __hip_bfloat16 Ps[4][16 * 64];  // 8 KB, per-wave P
    char* KsB = (char*)Ks;
    char* VTB = (char*)VTs;

    const int tid = threadIdx.x;
    const int bid = blockIdx.x;
    const int wgid = (bid & 7) * 64 + (bid >> 3);
    const int qb = wgid & 7, b = wgid >> 3;
    const int wid = tid >> 6, lane = tid & 63;
    const int l15 = lane & 15, lg = lane >> 4;
    char* PsB = (char*)(&Ps[wid][0]);

    short8 qf[8];
    const __hip_bfloat16* qrow = q + ((size_t)(b * 512 + qb * 64 + wid * 16 + l15)) * 256;
#pragma unroll
    for (int ks = 0; ks < 8; ++ks) qf[ks] = *(const short8*)(qrow + ks * 32 + lg * 8);

    float m_[4], lsum[4];
    floatx4 o[16];
#pragma unroll
    for (int r = 0; r < 4; ++r) { m_[r] = -1e30f; lsum[r] = 0.f; }
#pragma unroll
    for (int dt = 0; dt < 16; ++dt) o[dt] = (floatx4){0.f, 0.f, 0.f, 0.f};

    const int vkv = lane;
    const int vd0 = wid * 8;

    for (int c = 0; c <= qb; ++c) {
        const size_t kvbase = (size_t)(b * 512 + c * 64) * 256;
#pragma unroll
        for (int s = 0; s < 8; ++s) {
            int o_ = s * 4096 + tid * 16;
            int row = o_ >> 9;
            int so = o_ ^ ((row & 7) << 4);
            const __hip_bfloat16* src = k + kvbase + (size_t)row * 256 + ((so & 511) >> 1);
            GLOAD_LDS16(src, KsB + o_);
        }
#pragma unroll
        for (int it = 0; it < 8; ++it) {
            int dbase = vd0 + it * 32;
            short8 vv = *(const short8*)(v + kvbase + (size_t)vkv * 256 + dbase);
#pragma unroll
            for (int j = 0; j < 8; ++j) {
                int d = dbase + j;
                int addr = (d * 128 + vkv * 2) ^ ((d & 7) << 4);
                *(short*)(VTB + addr) = vv[j];
            }
        }
        __syncthreads();

        floatx4 s4[4];
#pragma unroll
        for (int t = 0; t < 4; ++t) s4[t] = (floatx4){0.f, 0.f, 0.f, 0.f};
#pragma unroll
        for (int ks = 0; ks < 8; ++ks) {
#pragma unroll
            for (int t = 0; t < 4; ++t) {
                int kv = t * 16 + l15;
                short8 kf = *(const short8*)(KsB + kv * 512 + ((ks * 64 + lg * 16) ^ ((kv & 7) << 4)));
                s4[t] = mfma16(qf[ks], kf, s4[t]);
            }
        }
        if (c == qb) {
#pragma unroll
            for (int t = 0; t < 4; ++t) {
                int kvl = t * 16 + l15;
#pragma unroll
                for (int r = 0; r < 4; ++r)
                    if (kvl > wid * 16 + lg * 4 + r) s4[t][r] = -1e30f;
            }
        }
        float pm[4], alpha[4], rs[4];
#pragma unroll
        for (int r = 0; r < 4; ++r)
            pm[r] = fmaxf(fmaxf(s4[0][r], s4[1][r]), fmaxf(s4[2][r], s4[3][r]));
#pragma unroll
        for (int off = 1; off <= 8; off <<= 1)
#pragma unroll
            for (int r = 0; r < 4; ++r) pm[r] = fmaxf(pm[r], __shfl_xor(pm[r], off));
#pragma unroll
        for (int r = 0; r < 4; ++r) {
            float mn = fmaxf(m_[r], pm[r]);
            alpha[r] = exp2f(m_[r] - mn);
            m_[r] = mn;
        }
#pragma unroll
        for (int t = 0; t < 4; ++t)
#pragma unroll
            for (int r = 0; r < 4; ++r) s4[t][r] = exp2f(s4[t][r] - m_[r]);
#pragma unroll
        for (int r = 0; r < 4; ++r) rs[r] = s4[0][r] + s4[1][r] + s4[2][r] + s4[3][r];
#pragma unroll
        for (int off = 1; off <= 8; off <<= 1)
#pragma unroll
            for (int r = 0; r < 4; ++r) rs[r] += __shfl_xor(rs[r], off);
#pragma unroll
        for (int r = 0; r < 4; ++r) lsum[r] = lsum[r] * alpha[r] + rs[r];
#pragma unroll
        for (int dt = 0; dt < 16; ++dt) {
            o[dt][0] *= alpha[0]; o[dt][1] *= alpha[1];
            o[dt][2] *= alpha[2]; o[dt][3] *= alpha[3];
        }
#pragma unroll
        for (int t = 0; t < 4; ++t)
#pragma unroll
            for (int r = 0; r < 4; ++r) {
                int qq = lg * 4 + r;
                int addr = (qq * 128 + (t * 16 + l15) * 2) ^ ((qq & 7) << 4);
                *(short*)(PsB + addr) = f2bf(s4[t][r]);
            }
#pragma unroll
        for (int h = 0; h < 2; ++h) {
            short8 pa = *(const short8*)(PsB + l15 * 128 + ((h * 64 + lg * 16) ^ ((l15 & 7) << 4)));
#pragma unroll
            for (int dt = 0; dt < 16; ++dt) {
                int d = dt * 16 + l15;
                short8 vb = *(const short8*)(VTB + d * 128 + ((h * 64 + lg * 16) ^ ((d & 7) << 4)));
                o[dt] = mfma16(pa, vb, o[dt]);
            }
        }
        __syncthreads();
    }

    float inv[4];
#pragma unroll
    for (int r = 0; r < 4; ++r) inv[r] = 1.0f / lsum[r];
    size_t obase = ((size_t)(b * 512 + qb * 64 + wid * 16 + lg * 4)) * 256 + l15;
#pragma unroll
    for (int dt = 0; dt < 16; ++dt)
#pragma unroll
        for (int r = 0; r < 4; ++r)
            out[obase + (size_t)r * 256 + dt * 16] = o[dt][r] * inv[r];
}

// ---------------- host launch ----------------
extern "C" void kernel_launch(void* const* d_in, const int* in_sizes, int n_in,
                              void* d_out, int out_size, void* d_ws, size_t ws_size,
                              hipStream_t stream) {
    const float* x  = (const float*)d_in[0];
    const float* Wq = (const float*)d_in[1];
    const float* bq = (const float*)d_in[2];
    const float* Wk = (const float*)d_in[3];
    const float* bk = (const float*)d_in[4];
    const float* Wv = (const float*)d_in[5];
    const float* bv = (const float*)d_in[6];
    float* out = (float*)d_out;

    char* ws = (char*)d_ws;
    __hip_bfloat16* WT = (__hip_bfloat16*)ws;                       // 1.5 MiB @ 0
    __hip_bfloat16* qo = (__hip_bfloat16*)(ws + (2u << 20));        // 16 MiB each
    __hip_bfloat16* ko = qo + (size_t)32768 * 256;
    __hip_bfloat16* vo = ko + (size_t)32768 * 256;

    wconv_kernel<<<dim3(768), dim3(256), 0, stream>>>(Wq, Wk, Wv, WT);
    proj_kernel<<<dim3(768), dim3(512), 0, stream>>>(x, WT, bq, bk, bv, qo, ko, vo);
    attn_kernel<<<dim3(512), dim3(256), 0, stream>>>(qo, ko, vo, out);
}